// Round 17
// baseline (236.830 us; speedup 1.0000x reference)
//
#include <hip/hip_runtime.h>

#define BB 8
#define TT 2048
#define CC 1024
#define WKV_L 32
#define WKV_NCH (TT / WKV_L)   // 64 chunks
#define WKV_LOG_NCH 6

typedef __bf16 bf16x8_t __attribute__((ext_vector_type(8)));
typedef float f32x4_t __attribute__((ext_vector_type(4)));
typedef unsigned short ushort8_t __attribute__((ext_vector_type(8)));

__device__ __forceinline__ unsigned short f2bf(float f) {
  unsigned u = __float_as_uint(f);
  u += 0x7fffu + ((u >> 16) & 1u);   // round-to-nearest-even
  return (unsigned short)(u >> 16);
}
__device__ __forceinline__ float bf2f(unsigned short s) {
  return __uint_as_float(((unsigned)s) << 16);
}

#define GLOAD16(gp, lp)                                                        \
  __builtin_amdgcn_global_load_lds(                                            \
      (const __attribute__((address_space(1))) void*)(gp),                     \
      (__attribute__((address_space(3))) void*)(lp), 16, 0, 0)

// ---- fused mix3 (grid-stride, proven) + weight casts --------------------
#define MIXGRID 2048
#define CASTGRID 256

__global__ __launch_bounds__(256) void mix3_castw_kernel(
    const float* __restrict__ x, const float* __restrict__ tmk,
    const float* __restrict__ tmv, const float* __restrict__ tmr,
    unsigned short* __restrict__ xk, unsigned short* __restrict__ xv,
    unsigned short* __restrict__ xr,
    const float* __restrict__ w0, const float* __restrict__ w1,
    const float* __restrict__ w2, const float* __restrict__ w3,
    unsigned short* __restrict__ o0, unsigned short* __restrict__ o1,
    unsigned short* __restrict__ o2, unsigned short* __restrict__ o3) {
  const int bid = blockIdx.x;
  const int tid = threadIdx.x;
  if (bid < MIXGRID) {
    const size_t total8 = (size_t)BB * TT * CC / 8;
    for (size_t i = (size_t)bid * 256 + tid; i < total8;
         i += (size_t)MIXGRID * 256) {
      size_t e = i * 8;
      int c = (int)(e & (CC - 1));
      int t = (int)((e >> 10) & (TT - 1));
      float4 xa = *(const float4*)(x + e);
      float4 xb = *(const float4*)(x + e + 4);
      float4 pa = make_float4(0.f, 0.f, 0.f, 0.f), pb = pa;
      if (t > 0) {
        pa = *(const float4*)(x + e - CC);
        pb = *(const float4*)(x + e - CC + 4);
      }
      float4 mka = *(const float4*)(tmk + c), mkb = *(const float4*)(tmk + c + 4);
      float4 mva = *(const float4*)(tmv + c), mvb = *(const float4*)(tmv + c + 4);
      float4 mra = *(const float4*)(tmr + c), mrb = *(const float4*)(tmr + c + 4);
      ushort8_t ok, ov, orr;
#define MIX1(dst, idx, xv_, pv_, m_) dst[idx] = f2bf(xv_ * m_ + pv_ * (1.f - m_));
      MIX1(ok, 0, xa.x, pa.x, mka.x) MIX1(ok, 1, xa.y, pa.y, mka.y)
      MIX1(ok, 2, xa.z, pa.z, mka.z) MIX1(ok, 3, xa.w, pa.w, mka.w)
      MIX1(ok, 4, xb.x, pb.x, mkb.x) MIX1(ok, 5, xb.y, pb.y, mkb.y)
      MIX1(ok, 6, xb.z, pb.z, mkb.z) MIX1(ok, 7, xb.w, pb.w, mkb.w)
      MIX1(ov, 0, xa.x, pa.x, mva.x) MIX1(ov, 1, xa.y, pa.y, mva.y)
      MIX1(ov, 2, xa.z, pa.z, mva.z) MIX1(ov, 3, xa.w, pa.w, mva.w)
      MIX1(ov, 4, xb.x, pb.x, mvb.x) MIX1(ov, 5, xb.y, pb.y, mvb.y)
      MIX1(ov, 6, xb.z, pb.z, mvb.z) MIX1(ov, 7, xb.w, pb.w, mvb.w)
      MIX1(orr, 0, xa.x, pa.x, mra.x) MIX1(orr, 1, xa.y, pa.y, mra.y)
      MIX1(orr, 2, xa.z, pa.z, mra.z) MIX1(orr, 3, xa.w, pa.w, mra.w)
      MIX1(orr, 4, xb.x, pb.x, mrb.x) MIX1(orr, 5, xb.y, pb.y, mrb.y)
      MIX1(orr, 6, xb.z, pb.z, mrb.z) MIX1(orr, 7, xb.w, pb.w, mrb.w)
#undef MIX1
      *(ushort8_t*)(xk + e) = ok;
      *(ushort8_t*)(xv + e) = ov;
      *(ushort8_t*)(xr + e) = orr;
    }
  } else {
    const int n4 = CC * CC / 4;   // per weight
    for (int i = (bid - MIXGRID) * 256 + tid; i < 4 * n4;
         i += CASTGRID * 256) {
      int sel = i / n4;
      int j = i - sel * n4;
      const float* w = sel == 0 ? w0 : sel == 1 ? w1 : sel == 2 ? w2 : w3;
      unsigned short* o = sel == 0 ? o0 : sel == 1 ? o1 : sel == 2 ? o2 : o3;
      float4 v = ((const float4*)w)[j];
      ushort4 u;
      u.x = f2bf(v.x); u.y = f2bf(v.y); u.z = f2bf(v.z); u.w = f2bf(v.w);
      ((ushort4*)o)[j] = u;
    }
  }
}

// ---- 256x256 GEMM, 2 barriers/K-tile (R16 liveness bug FIXED) -----------
// Interval A(t): [read bF1(t) | MFMA(0,0)(0,1) | refill aF<-A-h1(t) |
//                 stage A0B0(t+2) | vmcnt(8) | bar]
// Interval B(t): [MFMA(1,0)(1,1) | read aF0/bF0(t+1) | stage A1B1(t+2) |
//                 vmcnt(8) | bar]
// R16 bug: LOADA(1) sat BEFORE MFMAQ(0,0/0,1) which still needed aF=A-h0
// (single-buffered) -> mh0 rows computed with A-h1. Fix: refill after (0,1).
// vmcnt induction (stages of 2 insts): entering A(t) = [A0,B0,A1,B1](t+1)=8.
// End-A: +A0B0(t+2) =12 -> vmcnt(8) retires A0B0(t+1) (deadline B(t) reads).
// End-B: +A1B1(t+2) =12 -> vmcnt(8) retires A1B1(t+1) (deadline A(t+1) read).
// Boundaries: t=NT8-2 -> vmcnt(4)@A, vmcnt(0)@B; t=NT8-1 none.
// bF1 read at A-start: published by end-B(t-1); lgkm covered by MFMAQ(0,0).
// LDS WARs: every read lgkm-completes >=16 MFMA + barrier + ~400cy gload
// write-latency before the same-region (parity t&1, overwritten by t+2)
// staging write lands. 120 VGPR, no spill.
#define NT8 (CC / 64)   // 16 K-tiles

template <typename EPI>
__device__ __forceinline__ void gemm8_body(unsigned short* lds8,
                                           const unsigned short* __restrict__ A,
                                           const unsigned short* __restrict__ Bm,
                                           int tm, int tn, EPI epi) {
  const int tid = threadIdx.x;
  const int lane = tid & 63;
  const int wid = tid >> 6;
  const int wr = wid >> 2;   // 0..1
  const int wc = wid & 3;    // 0..3
  const int fr = lane & 15;
  const int fk = lane >> 4;  // 0..3

  const int srow = tid >> 3;                          // 0..63
  const int gcol = (((tid & 7) ^ (srow & 7)) << 3);   // pre-swizzled global col
  const unsigned short* Ag = A + (size_t)(tm * 256 + srow) * CC + gcol;
  const unsigned short* Bg = Bm + (size_t)(tn * 256 + srow) * CC + gcol;
  const int ldst = tid << 3;                          // linear LDS dest (elems)

  const int ab0 = (wr * 16 + fr) * 64;                // A base (elems, + parity)
  const int bb0 = 32768 + (wc * 16 + fr) * 64;        // B base
  const int sx0 = ((fk ^ (fr & 7)) << 3);             // read-side un-swizzle, kk=0
  const int sx1 = (((4 + fk) ^ (fr & 7)) << 3);       // kk=1

  bf16x8_t aF[4][2];      // single-buffered A half
  bf16x8_t bF[2][2][2];   // [half][j][kk], each half single-buffered
  f32x4_t acc[8][4] = {};

#define STG_A(T, H)                                                            \
  {                                                                            \
    const unsigned short* g_ = Ag + (size_t)((H) * 128) * CC + (T) * 64;       \
    unsigned short* l_ = &lds8[(((T) & 1) << 14) + (H) * 8192 + ldst];         \
    GLOAD16(g_, l_);                                                           \
    GLOAD16(g_ + (size_t)64 * CC, l_ + 4096);                                  \
  }
#define STG_B(T, H)                                                            \
  {                                                                            \
    const unsigned short* g_ = Bg + (size_t)((H) * 128) * CC + (T) * 64;       \
    unsigned short* l_ = &lds8[32768 + (((T) & 1) << 14) + (H) * 8192 + ldst]; \
    GLOAD16(g_, l_);                                                           \
    GLOAD16(g_ + (size_t)64 * CC, l_ + 4096);                                  \
  }
#define LOADA(MH, AB)                                                          \
  _Pragma("unroll") for (int i_ = 0; i_ < 4; ++i_) {                           \
    aF[i_][0] = *(const bf16x8_t*)&lds8[(AB) + ((MH) * 4 + i_) * 2048 + sx0];  \
    aF[i_][1] = *(const bf16x8_t*)&lds8[(AB) + ((MH) * 4 + i_) * 2048 + sx1];  \
  }
#define LOADB(NH, BB2)                                                         \
  _Pragma("unroll") for (int j_ = 0; j_ < 2; ++j_) {                           \
    bF[NH][j_][0] = *(const bf16x8_t*)&lds8[(BB2) + ((NH) * 2 + j_) * 4096 + sx0]; \
    bF[NH][j_][1] = *(const bf16x8_t*)&lds8[(BB2) + ((NH) * 2 + j_) * 4096 + sx1]; \
  }
#define MFMAQ(MH, NH)                                                          \
  _Pragma("unroll") for (int i_ = 0; i_ < 4; ++i_)                             \
  _Pragma("unroll") for (int j_ = 0; j_ < 2; ++j_) {                           \
    acc[(MH) * 4 + i_][(NH) * 2 + j_] = __builtin_amdgcn_mfma_f32_16x16x32_bf16( \
        aF[i_][0], bF[NH][j_][0], acc[(MH) * 4 + i_][(NH) * 2 + j_], 0, 0, 0); \
    acc[(MH) * 4 + i_][(NH) * 2 + j_] = __builtin_amdgcn_mfma_f32_16x16x32_bf16( \
        aF[i_][1], bF[NH][j_][1], acc[(MH) * 4 + i_][(NH) * 2 + j_], 0, 0, 0); \
  }

  // prologue: tiles 0 AND 1 fully staged (16 insts); vmcnt(8) lands tile0;
  // barrier publishes; pre-read aF0/bF0 of tile0.
  STG_A(0, 0) STG_B(0, 0) STG_A(0, 1) STG_B(0, 1)
  STG_A(1, 0) STG_B(1, 0) STG_A(1, 1) STG_B(1, 1)
  asm volatile("s_waitcnt vmcnt(8)" ::: "memory");
  __builtin_amdgcn_s_barrier();
  LOADA(0, ab0) LOADB(0, bb0)

#pragma unroll
  for (int t = 0; t < NT8; ++t) {
    const int pc = (t & 1) << 14;
    const int pn = ((t + 1) & 1) << 14;
    // ---- Interval A: bF1 read; 32 MFMA on aF0; aF refill AFTER last aF0 use
    LOADB(1, bb0 + pc)
    __builtin_amdgcn_s_setprio(1);
    MFMAQ(0, 0)
    MFMAQ(0, 1)
    __builtin_amdgcn_s_setprio(0);
    LOADA(1, ab0 + pc)                                   // aF0 dead; refill A-h1(t)
    if (t + 2 < NT8) {
      STG_A(t + 2, 0) STG_B(t + 2, 0)
      asm volatile("s_waitcnt vmcnt(8)" ::: "memory");   // retires A0B0(t+1)
    } else if (t + 1 < NT8) {
      asm volatile("s_waitcnt vmcnt(4)" ::: "memory");
    }
    __builtin_amdgcn_s_barrier();
    // ---- Interval B: 32 MFMA on aF1; then next-tile A0/B0 reads
    __builtin_amdgcn_s_setprio(1);
    MFMAQ(1, 0)
    MFMAQ(1, 1)
    __builtin_amdgcn_s_setprio(0);
    if (t + 1 < NT8) { LOADA(0, ab0 + pn) LOADB(0, bb0 + pn) }
    if (t + 2 < NT8) {
      STG_A(t + 2, 1) STG_B(t + 2, 1)
      asm volatile("s_waitcnt vmcnt(8)" ::: "memory");   // retires A1B1(t+1)
    } else if (t + 1 < NT8) {
      asm volatile("s_waitcnt vmcnt(0)" ::: "memory");
    }
    __builtin_amdgcn_s_barrier();
  }

  // epilogue: C/D layout col=lane&15, row=fk*4+rg; frag (im,jn) at
  // rows wr*16+32*im, cols wc*16+64*jn (interleaved wave mapping)
#pragma unroll
  for (int im = 0; im < 8; ++im)
#pragma unroll
    for (int jn = 0; jn < 4; ++jn)
#pragma unroll
      for (int rg = 0; rg < 4; ++rg)
        epi((size_t)(tm * 256 + wr * 16 + im * 32 + (fk << 2) + rg) * CC +
                (size_t)(tn * 256 + wc * 16 + jn * 64 + fr),
            acc[im][jn][rg]);
#undef STG_A
#undef STG_B
#undef LOADA
#undef LOADB
#undef MFMAQ
}

// merged k/v/r projection: 768 blocks, XCD-swizzled, all outputs bf16
__global__ __launch_bounds__(512, 2) void gemm8_kvr(
    const unsigned short* __restrict__ xk, const unsigned short* __restrict__ xv,
    const unsigned short* __restrict__ xr, const unsigned short* __restrict__ Wk,
    const unsigned short* __restrict__ Wv, const unsigned short* __restrict__ Wr,
    unsigned short* __restrict__ kout, unsigned short* __restrict__ vout,
    unsigned short* __restrict__ rout) {
  __shared__ unsigned short lds8[65536];   // 128 KB
  int orig = blockIdx.x;
  int wg = (orig & 7) * 96 + (orig >> 3);
  int which = wg >> 8;        // 256 tiles per matrix
  int rr = wg & 255;
  int tm = rr >> 2;           // tn-fast within XCD chunk
  int tn = rr & 3;
  const unsigned short* A = which == 0 ? xk : which == 1 ? xv : xr;
  const unsigned short* Bm = which == 0 ? Wk : which == 1 ? Wv : Wr;
  unsigned short* o = which == 0 ? kout : which == 1 ? vout : rout;
  gemm8_body(lds8, A, Bm, tm, tn,
             [&](size_t off, float val) { o[off] = f2bf(val); });
}

// single GEMM (256 blocks, XCD-swizzled), fp32 out (final projection)
__global__ __launch_bounds__(512, 2) void gemm8_one(const unsigned short* __restrict__ A,
                         const unsigned short* __restrict__ Bm,
                         float* __restrict__ Cm) {
  __shared__ unsigned short lds8[65536];   // 128 KB
  int orig = blockIdx.x;
  int wg = (orig & 7) * 32 + (orig >> 3);
  int tm = wg >> 2;
  int tn = wg & 3;
  gemm8_body(lds8, A, Bm, tm, tn,
             [&](size_t off, float val) { Cm[off] = val; });
}

// ---- Chunk-parallel WKV scan, anchor-decay, 4 ch/thread, load pipeline ---
__global__ __launch_bounds__(256) void wkv_phase1(const unsigned short* __restrict__ k,
                           const unsigned short* __restrict__ v,
                           const float* __restrict__ wdec,
                           float* __restrict__ Sa, float* __restrict__ Sb,
                           float* __restrict__ Sp) {
  int idx = blockIdx.x * blockDim.x + threadIdx.x;  // (b*NCH + j)*(CC/4) + c4
  int c = (idx & (CC / 4 - 1)) << 2;
  int bj = idx >> 8;
  int j = bj & (WKV_NCH - 1);
  int b = bj >> WKV_LOG_NCH;
  float w[4], aa[4], bb[4], pp[4];
#pragma unroll
  for (int q = 0; q < 4; ++q) {
    w[q] = -__expf(wdec[c + q]);
    aa[q] = 0.f; bb[q] = 0.f; pp[q] = -1e38f;
  }
  size_t off = ((size_t)b * TT + (size_t)j * WKV_L) * CC + c;
  ushort4 kk = *(const ushort4*)(k + off);
  ushort4 vv = *(const ushort4*)(v + off);
  for (int t = 0; t < WKV_L; ++t) {
    size_t noff = off + ((t + 1 < WKV_L) ? CC : 0);
    ushort4 nk = *(const ushort4*)(k + noff);
    ushort4 nv = *(const ushort4*)(v + noff);
    const unsigned short* kp = (const unsigned short*)&kk;
    const unsigned short* vp = (const unsigned short*)&vv;
#pragma unroll
    for (int q = 0; q < 4; ++q) {
      float kt = bf2f(kp[q]);
      float vt = bf2f(vp[q]);
      pp[q] += w[q];
      float d = kt - pp[q];
      if (d > 8.f) { float s = __expf(-d); aa[q] *= s; bb[q] *= s; pp[q] = kt; d = 0.f; }
      float E = __expf(d);
      aa[q] = fmaf(E, vt, aa[q]); bb[q] += E;
    }
    kk = nk; vv = nv; off = noff;
  }
  size_t s = (size_t)bj * CC + c;
  *(float4*)(Sa + s) = make_float4(aa[0], aa[1], aa[2], aa[3]);
  *(float4*)(Sb + s) = make_float4(bb[0], bb[1], bb[2], bb[3]);
  *(float4*)(Sp + s) = make_float4(pp[0], pp[1], pp[2], pp[3]);
}

// serial scan over chunk summaries -> incoming state per chunk
__global__ __launch_bounds__(256) void wkv_phase2(const float* __restrict__ wdec,
                           const float* __restrict__ Sa, const float* __restrict__ Sb,
                           const float* __restrict__ Sp,
                           float* __restrict__ Ia, float* __restrict__ Ib,
                           float* __restrict__ Ip) {
  int idx = blockIdx.x * blockDim.x + threadIdx.x;  // b*CC + c
  if (idx >= BB * CC) return;
  int c = idx & (CC - 1);
  int b = idx >> 10;
  float wL = -__expf(wdec[c]) * (float)WKV_L;
  float aa = 0.f, bb = 0.f, pp = -1e38f;
  for (int j = 0; j < WKV_NCH; ++j) {
    size_t s = (size_t)(b * WKV_NCH + j) * CC + c;
    Ia[s] = aa; Ib[s] = bb; Ip[s] = pp;
    float pd = pp + wL;
    float ps = Sp[s];
    float q = fmaxf(pd, ps);
    float e1 = __expf(pd - q);
    float e2 = __expf(ps - q);
    aa = fmaf(e1, aa, e2 * Sa[s]);
    bb = fmaf(e1, bb, e2 * Sb[s]);
    pp = q;
  }
}

// phase3: anchor-decay replay + fused sigmoid(r)*y, 4 ch/thread, in-place,
// with t+1 load prefetch.
__global__ __launch_bounds__(256) void wkv_phase3(const unsigned short* __restrict__ k,
                           const unsigned short* __restrict__ v,
                           const unsigned short* r,
                           const float* __restrict__ wdec,
                           const float* __restrict__ u,
                           const float* __restrict__ Ia, const float* __restrict__ Ib,
                           const float* __restrict__ Ip,
                           unsigned short* out) {
  int idx = blockIdx.x * blockDim.x + threadIdx.x;
  int c = (idx & (CC / 4 - 1)) << 2;
  int bj = idx >> 8;
  int j = bj & (WKV_NCH - 1);
  int b = bj >> WKV_LOG_NCH;
  float w[4], uu[4], aa[4], bb[4], pp[4];
  size_t st = (size_t)bj * CC + c;
  float4 a4 = *(const float4*)(Ia + st);
  float4 b4 = *(const float4*)(Ib + st);
  float4 p4 = *(const float4*)(Ip + st);
  aa[0] = a4.x; aa[1] = a4.y; aa[2] = a4.z; aa[3] = a4.w;
  bb[0] = b4.x; bb[1] = b4.y; bb[2] = b4.z; bb[3] = b4.w;
  pp[0] = p4.x; pp[1] = p4.y; pp[2] = p4.z; pp[3] = p4.w;
#pragma unroll
  for (int q = 0; q < 4; ++q) {
    w[q] = -__expf(wdec[c + q]);
    uu[q] = u[c + q];
  }
  size_t off = ((size_t)b * TT + (size_t)j * WKV_L) * CC + c;
  ushort4 kk = *(const ushort4*)(k + off);
  ushort4 vv = *(const ushort4*)(v + off);
  ushort4 rr4 = *(const ushort4*)(r + off);
  for (int t = 0; t < WKV_L; ++t) {
    size_t noff = off + ((t + 1 < WKV_L) ? CC : 0);
    ushort4 nk = *(const ushort4*)(k + noff);
    ushort4 nv = *(const ushort4*)(v + noff);
    ushort4 nr = *(const ushort4*)(r + noff);
    const unsigned short* kp = (const unsigned short*)&kk;
    const unsigned short* vp = (const unsigned short*)&vv;
    const unsigned short* rp = (const unsigned short*)&rr4;
    ushort4 o4;
    unsigned short* op = (unsigned short*)&o4;
#pragma unroll
    for (int q = 0; q < 4; ++q) {
      float kt = bf2f(kp[q]);
      float vt = bf2f(vp[q]);
      float dy = fminf(uu[q] + kt - pp[q], 60.f);
      float Eu = __expf(dy);
      float y = fmaf(Eu, vt, aa[q]) / (bb[q] + Eu);
      float sr = 1.f / (1.f + __expf(-bf2f(rp[q])));
      op[q] = f2bf(sr * y);
      pp[q] += w[q];
      float d = kt - pp[q];
      if (d > 8.f) { float s = __expf(-d); aa[q] *= s; bb[q] *= s; pp[q] = kt; d = 0.f; }
      float E = __expf(d);
      aa[q] = fmaf(E, vt, aa[q]); bb[q] += E;
    }
    *(ushort4*)(out + off) = o4;
    kk = nk; vv = nv; rr4 = nr; off = noff;
  }
}

extern "C" void kernel_launch(void* const* d_in, const int* in_sizes, int n_in,
                              void* d_out, int out_size, void* d_ws, size_t ws_size,
                              hipStream_t stream) {
  const float* x    = (const float*)d_in[0];
  const float* tdec = (const float*)d_in[1];
  const float* tfir = (const float*)d_in[2];
  const float* tmk  = (const float*)d_in[3];
  const float* tmv  = (const float*)d_in[4];
  const float* tmr  = (const float*)d_in[5];
  const float* Wk   = (const float*)d_in[6];
  const float* Wv   = (const float*)d_in[7];
  const float* Wr   = (const float*)d_in[8];
  const float* Wo   = (const float*)d_in[9];

  const size_t M = (size_t)BB * TT;     // 16384
  const size_t mixbytes = M * CC * 2;   // 33.5 MB
  const size_t wbytes = (size_t)CC * CC * 2;
  const size_t nstate = (size_t)BB * WKV_NCH * CC;   // 512K

  // Layout (~209 MB peak, proven fit):
  char* ws = (char*)d_ws;
  unsigned short* xkb = (unsigned short*)ws;  ws += mixbytes;
  unsigned short* xvb = (unsigned short*)ws;  ws += mixbytes;
  unsigned short* xrb = (unsigned short*)ws;  ws += mixbytes;
  unsigned short* Wkb = (unsigned short*)ws; ws += wbytes;
  unsigned short* Wvb = (unsigned short*)ws; ws += wbytes;
  unsigned short* Wrb = (unsigned short*)ws; ws += wbytes;
  unsigned short* Wob = (unsigned short*)ws; ws += wbytes;
  unsigned short* kbuf = (unsigned short*)ws; ws += mixbytes;
  unsigned short* vbuf = (unsigned short*)ws; ws += mixbytes;
  unsigned short* rbuf = (unsigned short*)ws; ws += mixbytes;
  // states overlay the dead xk/xv regions (12.6 MB < 67 MB)
  char* so = (char*)xkb;
  float* Sa = (float*)so; so += nstate * 4;
  float* Sb = (float*)so; so += nstate * 4;
  float* Sp = (float*)so; so += nstate * 4;
  float* Ia = (float*)so; so += nstate * 4;
  float* Ib = (float*)so; so += nstate * 4;
  float* Ip = (float*)so; so += nstate * 4;

  dim3 blk(256);
  dim3 blk8(512);
  const int wkv_grid = (int)(nstate / 4 / 256);   // 512

  mix3_castw_kernel<<<MIXGRID + CASTGRID, blk, 0, stream>>>(
      x, tmk, tmv, tmr, xkb, xvb, xrb,
      Wk, Wv, Wr, Wo, Wkb, Wvb, Wrb, Wob);
  gemm8_kvr<<<768, blk8, 0, stream>>>(xkb, xvb, xrb, Wkb, Wvb, Wrb,
                                      kbuf, vbuf, rbuf);

  wkv_phase1<<<wkv_grid, blk, 0, stream>>>(kbuf, vbuf, tdec, Sa, Sb, Sp);
  wkv_phase2<<<(BB * CC + 255) / 256, blk, 0, stream>>>(tdec, Sa, Sb, Sp, Ia, Ib, Ip);
  wkv_phase3<<<wkv_grid, blk, 0, stream>>>(kbuf, vbuf, rbuf, tdec, tfir,
                                           Ia, Ib, Ip, rbuf);  // in-place gate

  gemm8_one<<<256, blk8, 0, stream>>>(rbuf, Wob, (float*)d_out);
}